// Round 1
// baseline (427.001 us; speedup 1.0000x reference)
//
#include <hip/hip_runtime.h>
#include <math.h>

#define B_   16
#define L_   256
#define V_   50000
#define NV_  50100
#define E_   128
#define H_   128
#define G4_  512
#define CHUNK_ 1566   // ceil(50100/32)

__device__ __forceinline__ float sigm(float x){ return 1.0f/(1.0f+__expf(-x)); }
__device__ __forceinline__ float tanh_fast(float x){
  x = fminf(15.0f, fmaxf(-15.0f, x));
  float t = __expf(2.0f*x);
  return (t-1.0f)/(t+1.0f);
}

// ---------------- K1: encoder xg = emb[tok] @ W_ih^T + b ----------------
// grid 512 blocks (8 rows each), 512 threads (one gate output each)
__global__ __launch_bounds__(512) void enc_xg_kernel(
    const int* __restrict__ tok, const float* __restrict__ emb,
    const float* __restrict__ Wih, const float* __restrict__ bias,
    float* __restrict__ xg)
{
  __shared__ float sx[8*128];
  int r0 = blockIdx.x*8;
  int t = threadIdx.x;
  for (int i=t; i<8*128; i+=512){
    int r=i>>7, e=i&127;
    sx[i] = emb[(size_t)tok[r0+r]*E_ + e];
  }
  __syncthreads();
  int g = t;
  float acc[8];
  #pragma unroll
  for (int r=0;r<8;r++) acc[r]=0.f;
  const float4* wr = (const float4*)(Wih + (size_t)g*E_);
  #pragma unroll 4
  for (int i=0;i<32;i++){
    float4 w = wr[i];
    #pragma unroll
    for (int r=0;r<8;r++){
      float4 x = ((const float4*)(sx + r*128))[i];
      acc[r] += w.x*x.x + w.y*x.y + w.z*x.z + w.w*x.w;
    }
  }
  float bg = bias[g];
  #pragma unroll
  for (int r=0;r<8;r++) xg[(size_t)(r0+r)*G4_ + g] = acc[r] + bg;
}

// ---------------- K2: encoder LSTM recurrence ----------------
// 16 blocks (one per batch), 512 threads (one gate each), W_hh row in VGPRs
__global__ __launch_bounds__(512) void enc_lstm_kernel(
    const float* __restrict__ xg, const float* __restrict__ Whh,
    float* __restrict__ enc_out)
{
  int b = blockIdx.x;
  int g = threadIdx.x;
  float4 w[32];
  const float4* wrow = (const float4*)(Whh + (size_t)g*H_);
  #pragma unroll
  for (int i=0;i<32;i++) w[i]=wrow[i];

  __shared__ float sh_h[128];
  __shared__ float sh_g[512];
  if (g<128) sh_h[g]=0.f;
  float c = 0.f;
  const float* xgb = xg + (size_t)b*L_*G4_;
  float* eob = enc_out + (size_t)b*L_*H_;
  __syncthreads();

  float xcur = xgb[g];
  for (int t=0;t<L_;t++){
    float xnext = (t<L_-1) ? xgb[(t+1)*G4_ + g] : 0.f;  // prefetch
    float acc = xcur;
    #pragma unroll
    for (int i=0;i<32;i++){
      float4 h4 = ((const float4*)sh_h)[i];
      float4 wv = w[i];
      acc += wv.x*h4.x + wv.y*h4.y + wv.z*h4.z + wv.w*h4.w;
    }
    sh_g[g] = acc;
    __syncthreads();
    if (g < 128){
      float iv = sh_g[g], fv = sh_g[128+g], gv = sh_g[256+g], ov = sh_g[384+g];
      c = sigm(fv)*c + sigm(iv)*tanh_fast(gv);
      float h = sigm(ov)*tanh_fast(c);
      sh_h[g] = h;
      eob[t*H_ + g] = h;
    }
    __syncthreads();
    xcur = xnext;
  }
}

// ---------------- K3: copy-attention raw scores ----------------
// grid B*L blocks, 128 threads; mask almost always 0 -> early out
__global__ __launch_bounds__(128) void copy_score1_kernel(
    const int* __restrict__ src, const int* __restrict__ prev,
    const float* __restrict__ enc_out, const float* __restrict__ cW,
    const float* __restrict__ dstate, float* __restrict__ s)
{
  int bl = blockIdx.x; int b = bl>>8;
  if (src[bl] != prev[b]){ if (threadIdx.x==0) s[bl]=0.f; return; }
  __shared__ float se[128];
  __shared__ float sred[2];
  int g = threadIdx.x;
  se[g] = enc_out[(size_t)bl*H_ + g];
  __syncthreads();
  const float4* wr = (const float4*)(cW + (size_t)g*H_);
  float acc=0.f;
  #pragma unroll
  for (int i=0;i<32;i++){
    float4 wv=wr[i]; float4 e=((const float4*)se)[i];
    acc += wv.x*e.x + wv.y*e.y + wv.z*e.z + wv.w*e.w;
  }
  float v = tanhf(acc)*dstate[b*H_+g];
  #pragma unroll
  for (int o=32;o;o>>=1) v += __shfl_down(v,o);
  if ((g&63)==0) sred[g>>6]=v;
  __syncthreads();
  if (g==0) s[bl]=sred[0]+sred[1];
}

// ---------------- K4: copy softmax + copy_state ----------------
__global__ __launch_bounds__(256) void copy_softmax_state_kernel(
    const float* __restrict__ s, const float* __restrict__ enc_out,
    float* __restrict__ cstate)
{
  int b=blockIdx.x, t=threadIdx.x;
  __shared__ float sw[256];
  __shared__ float sred[4];
  float v = s[b*L_+t];
  float m=v;
  #pragma unroll
  for (int o=32;o;o>>=1) m=fmaxf(m,__shfl_down(m,o));
  if ((t&63)==0) sred[t>>6]=m;
  __syncthreads();
  m = fmaxf(fmaxf(sred[0],sred[1]),fmaxf(sred[2],sred[3]));
  __syncthreads();
  float e = __expf(v-m);
  float z = e;
  #pragma unroll
  for (int o=32;o;o>>=1) z += __shfl_down(z,o);
  if ((t&63)==0) sred[t>>6]=z;
  __syncthreads();
  z = sred[0]+sred[1]+sred[2]+sred[3];
  sw[t] = e/z;
  __syncthreads();
  if (t<128){
    float acc=0.f;
    for (int l=0;l<256;l++) acc += sw[l]*enc_out[((size_t)b*L_+l)*H_ + t];
    cstate[b*H_+t]=acc;
  }
}

// ---------------- K5: decoder single LSTM step (h0=c0=0) ----------------
__global__ __launch_bounds__(512) void dec_step_kernel(
    const int* __restrict__ prev, const float* __restrict__ emb,
    const float* __restrict__ cstate, const float* __restrict__ Wih,
    const float* __restrict__ bias, float* __restrict__ rnn)
{
  int b=blockIdx.x, g=threadIdx.x;
  __shared__ float sin_[256];
  __shared__ float sg[512];
  if (g<128) sin_[g]=emb[(size_t)prev[b]*E_+g];
  else if (g<256) sin_[g]=cstate[b*H_ + (g-128)];
  __syncthreads();
  const float4* wr = (const float4*)(Wih + (size_t)g*256);
  float acc = bias[g];
  #pragma unroll 8
  for (int i=0;i<64;i++){
    float4 wv=wr[i]; float4 x=((const float4*)sin_)[i];
    acc += wv.x*x.x + wv.y*x.y + wv.z*x.z + wv.w*x.w;
  }
  sg[g]=acc;
  __syncthreads();
  if (g<128){
    float iv=sg[g], gv=sg[256+g], ov=sg[384+g];   // f-gate * c0 = 0
    float cc = sigm(iv)*tanhf(gv);
    rnn[b*H_+g] = sigm(ov)*tanhf(cc);
  }
}

// ---------------- K6: attention + attn_out ----------------
__global__ __launch_bounds__(256) void attn_kernel(
    const int* __restrict__ src, const float* __restrict__ rnn,
    const float* __restrict__ enc_out, const float* __restrict__ aW,
    const float* __restrict__ oW, const float* __restrict__ ob,
    float* __restrict__ attn_out)
{
  int b=blockIdx.x, t=threadIdx.x;
  __shared__ float sr[128], sq[128], sctx[128];
  __shared__ float sc[256];
  __shared__ float sred[4];
  if (t<128) sr[t]=rnn[b*H_+t];
  __syncthreads();
  if (t<128){
    const float4* wr=(const float4*)(aW + (size_t)t*H_);
    float acc=0.f;
    #pragma unroll
    for (int i=0;i<32;i++){
      float4 wv=wr[i]; float4 x=((const float4*)sr)[i];
      acc += wv.x*x.x + wv.y*x.y + wv.z*x.z + wv.w*x.w;
    }
    sq[t]=acc;
  }
  __syncthreads();
  {
    const float4* e4=(const float4*)(enc_out + ((size_t)b*L_+t)*H_);
    float acc=0.f;
    #pragma unroll
    for (int i=0;i<32;i++){
      float4 e=e4[i]; float4 q=((const float4*)sq)[i];
      acc += e.x*q.x + e.y*q.y + e.z*q.z + e.w*q.w;
    }
    if (src[b*L_+t]==0) acc=-INFINITY;
    sc[t]=acc;
  }
  __syncthreads();
  // softmax over sc[256]
  float v = sc[t];
  float m=v;
  #pragma unroll
  for (int o=32;o;o>>=1) m=fmaxf(m,__shfl_down(m,o));
  if ((t&63)==0) sred[t>>6]=m;
  __syncthreads();
  m = fmaxf(fmaxf(sred[0],sred[1]),fmaxf(sred[2],sred[3]));
  __syncthreads();
  float e = __expf(v-m);
  float z = e;
  #pragma unroll
  for (int o=32;o;o>>=1) z += __shfl_down(z,o);
  if ((t&63)==0) sred[t>>6]=z;
  __syncthreads();
  z = sred[0]+sred[1]+sred[2]+sred[3];
  sc[t] = e/z;
  __syncthreads();
  if (t<128){
    float acc=0.f;
    for (int l=0;l<256;l++) acc += sc[l]*enc_out[((size_t)b*L_+l)*H_ + t];
    sctx[t]=acc;
  }
  __syncthreads();
  if (t<128){
    float acc=ob[t];
    const float4* wr=(const float4*)(oW + (size_t)t*256);
    #pragma unroll
    for (int i=0;i<32;i++){
      float4 wv=wr[i]; float4 x=((const float4*)sr)[i];
      acc += wv.x*x.x + wv.y*x.y + wv.z*x.z + wv.w*x.w;
    }
    #pragma unroll
    for (int i=0;i<32;i++){
      float4 wv=wr[32+i]; float4 x=((const float4*)sctx)[i];
      acc += wv.x*x.x + wv.y*x.y + wv.z*x.z + wv.w*x.w;
    }
    attn_out[b*H_+t]=tanhf(acc);
  }
}

// ---------------- K7a: first-occurrence aggregation of enc_out by token ----------------
__global__ __launch_bounds__(256) void copy_agg_kernel(
    const int* __restrict__ stw, const float* __restrict__ enc_out,
    float* __restrict__ agg, int* __restrict__ replist, int* __restrict__ repcnt)
{
  int b=blockIdx.x, l=threadIdx.x;
  __shared__ int stok[256];
  __shared__ int scnt;
  stok[l] = stw[b*L_+l];
  if (l==0) scnt=0;
  __syncthreads();
  int tok = stok[l];
  int first=0;
  while (stok[first]!=tok) first++;
  if (first==l){
    int myidx = atomicAdd(&scnt,1);
    float4 acc[32];
    #pragma unroll
    for (int i=0;i<32;i++) acc[i]=make_float4(0.f,0.f,0.f,0.f);
    for (int l2=l; l2<L_; l2++){
      if (stok[l2]==tok){
        const float4* e=(const float4*)(enc_out + ((size_t)b*L_+l2)*H_);
        #pragma unroll
        for (int i=0;i<32;i++){
          float4 v=e[i];
          acc[i].x+=v.x; acc[i].y+=v.y; acc[i].z+=v.z; acc[i].w+=v.w;
        }
      }
    }
    float4* dst=(float4*)(agg + ((size_t)b*L_+l)*H_);
    #pragma unroll
    for (int i=0;i<32;i++) dst[i]=acc[i];
    replist[b*L_+myidx]=l;
  }
  __syncthreads();
  if (l==0) repcnt[b]=scnt;
}

// ---------------- K9: gen logits + masks -> total ----------------
__global__ __launch_bounds__(256) void gen_logits_kernel(
    const float* __restrict__ attn_out, const float* __restrict__ gW,
    const int* __restrict__ oovc, float* __restrict__ total)
{
  __shared__ float sa[B_*H_];
  __shared__ float sw[64*129];
  int t=threadIdx.x;
  int v0=blockIdx.x*64;
  for (int i=t;i<B_*H_;i+=256) sa[i]=attn_out[i];
  for (int i=t;i<64*32;i+=256){
    int r=i>>5, cc=i&31;
    if (v0+r<NV_){
      float4 wv = ((const float4*)(gW + (size_t)(v0+r)*H_))[cc];
      float* dst = sw + r*129 + cc*4;
      dst[0]=wv.x; dst[1]=wv.y; dst[2]=wv.z; dst[3]=wv.w;
    }
  }
  __syncthreads();
  int vl=t&63, bq=t>>6;
  int v=v0+vl;
  if (v>=NV_) return;
  float acc[4]={0.f,0.f,0.f,0.f};
  const float* wrow = sw + vl*129;
  #pragma unroll 8
  for (int h4=0; h4<32; h4++){
    float w0=wrow[h4*4+0], w1=wrow[h4*4+1], w2=wrow[h4*4+2], w3=wrow[h4*4+3];
    #pragma unroll
    for (int k=0;k<4;k++){
      float4 a = ((const float4*)(sa + (bq*4+k)*H_))[h4];
      acc[k] += w0*a.x + w1*a.y + w2*a.z + w3*a.w;
    }
  }
  #pragma unroll
  for (int k=0;k<4;k++){
    int b=bq*4+k;
    float o = (v==1 || v >= V_ + oovc[b]) ? -INFINITY : acc[k];
    total[(size_t)b*NV_ + v] = o;
  }
}

// ---------------- K7b: sparse copy scores added into total ----------------
__global__ __launch_bounds__(128) void copy_score2_kernel(
    const int* __restrict__ stw, const float* __restrict__ agg,
    const float* __restrict__ cW, const float* __restrict__ attn_out,
    const int* __restrict__ replist, const int* __restrict__ repcnt,
    float* __restrict__ total)
{
  int b=blockIdx.x;
  int cnt=repcnt[b];
  int g=threadIdx.x;
  __shared__ float srow[128];
  __shared__ float sred[2];
  float aog = attn_out[b*H_+g];
  float4 w[32];
  const float4* wrow=(const float4*)(cW + (size_t)g*H_);
  #pragma unroll
  for (int i=0;i<32;i++) w[i]=wrow[i];
  for (int ri=blockIdx.y; ri<cnt; ri+=gridDim.y){
    int l = replist[b*L_+ri];
    srow[g] = agg[((size_t)b*L_+l)*H_+g];
    __syncthreads();
    float acc=0.f;
    #pragma unroll
    for (int i=0;i<32;i++){
      float4 e=((const float4*)srow)[i]; float4 wv=w[i];
      acc += wv.x*e.x + wv.y*e.y + wv.z*e.z + wv.w*e.w;
    }
    float v = tanhf(acc)*aog;
    #pragma unroll
    for (int o=32;o;o>>=1) v += __shfl_down(v,o);
    if ((g&63)==0) sred[g>>6]=v;
    __syncthreads();
    if (g==0){
      int vtok = stw[b*L_+l];
      total[(size_t)b*NV_ + vtok] += sred[0]+sred[1];
    }
    __syncthreads();
  }
}

// ---------------- K10: vocab softmax (chunked two-pass) ----------------
__global__ __launch_bounds__(256) void vocab_pass1_kernel(
    const float* __restrict__ total, float* __restrict__ pmax, float* __restrict__ psum)
{
  int b=blockIdx.x, j=blockIdx.y, t=threadIdx.x;
  int lo=j*CHUNK_, hi=min(lo+CHUNK_, NV_);
  const float* row = total + (size_t)b*NV_;
  __shared__ float sred[4];
  float m=-INFINITY;
  for (int i=lo+t;i<hi;i+=256) m=fmaxf(m,row[i]);
  #pragma unroll
  for (int o=32;o;o>>=1) m=fmaxf(m,__shfl_down(m,o));
  if ((t&63)==0) sred[t>>6]=m;
  __syncthreads();
  m = fmaxf(fmaxf(sred[0],sred[1]),fmaxf(sred[2],sred[3]));
  __syncthreads();
  float s=0.f;
  if (m > -INFINITY){
    for (int i=lo+t;i<hi;i+=256) s += __expf(row[i]-m);
    #pragma unroll
    for (int o=32;o;o>>=1) s += __shfl_down(s,o);
  }
  if ((t&63)==0) sred[t>>6]=s;
  __syncthreads();
  if (t==0){ pmax[b*32+j]=m; psum[b*32+j]=sred[0]+sred[1]+sred[2]+sred[3]; }
}

__global__ void vocab_pass2_kernel(const float* __restrict__ pmax,
                                   const float* __restrict__ psum, float* __restrict__ MZ)
{
  int b=blockIdx.x, t=threadIdx.x; // 32 threads
  float mj = pmax[b*32+t];
  float m = mj;
  #pragma unroll
  for (int o=16;o;o>>=1) m=fmaxf(m,__shfl_down(m,o));
  m = __shfl(m,0);
  float z = psum[b*32+t]*__expf(mj-m);
  #pragma unroll
  for (int o=16;o;o>>=1) z += __shfl_down(z,o);
  if (t==0){ MZ[b]=m; MZ[16+b]=z; }
}

__global__ __launch_bounds__(256) void vocab_pass3_kernel(
    float* __restrict__ total, const float* __restrict__ MZ)
{
  int b=blockIdx.x, j=blockIdx.y, t=threadIdx.x;
  int lo=j*CHUNK_, hi=min(lo+CHUNK_, NV_);
  float m=MZ[b], rz=1.0f/MZ[16+b];
  float* row = total + (size_t)b*NV_;
  for (int i=lo+t;i<hi;i+=256) row[i] = __expf(row[i]-m)*rz;
}

// ---------------- launch ----------------
extern "C" void kernel_launch(void* const* d_in, const int* in_sizes, int n_in,
                              void* d_out, int out_size, void* d_ws, size_t ws_size,
                              hipStream_t stream)
{
  const int*   src_tokens = (const int*)d_in[0];
  const int*   prev_tok   = (const int*)d_in[2];
  const int*   stw        = (const int*)d_in[4];
  const int*   oovc       = (const int*)d_in[5];
  const float* dstate     = (const float*)d_in[6];
  const float* emb        = (const float*)d_in[7];
  const float* enc_Wih    = (const float*)d_in[8];
  const float* enc_Whh    = (const float*)d_in[9];
  const float* enc_b      = (const float*)d_in[10];
  const float* dec_Wih    = (const float*)d_in[11];
  const float* dec_b      = (const float*)d_in[13];
  const float* attn_W     = (const float*)d_in[14];
  const float* out_W      = (const float*)d_in[15];
  const float* out_b      = (const float*)d_in[16];
  const float* copy_W     = (const float*)d_in[17];
  const float* gen_W      = (const float*)d_in[18];

  float* out      = (float*)d_out;
  float* total    = out;                                 // B*NV
  float* enc_out  = out + (size_t)B_*NV_;                // B*L*H
  float* attn_out = enc_out + (size_t)B_*L_*H_;          // B*H

  float* ws     = (float*)d_ws;
  float* xg     = ws;                                    // 2097152
  float* agg    = xg + (size_t)B_*L_*G4_;                // 524288
  float* scopy  = agg + (size_t)B_*L_*H_;                // 4096
  float* cstate = scopy + B_*L_;                         // 2048
  float* rnn    = cstate + B_*H_;                        // 2048
  float* pmax   = rnn + B_*H_;                           // 512
  float* psum   = pmax + 512;                            // 512
  float* MZ     = psum + 512;                            // 32
  int*   replist= (int*)(MZ + 32);                       // 4096
  int*   repcnt = replist + B_*L_;                       // 16

  enc_xg_kernel<<<B_*L_/8, 512, 0, stream>>>(src_tokens, emb, enc_Wih, enc_b, xg);
  enc_lstm_kernel<<<B_, 512, 0, stream>>>(xg, enc_Whh, enc_out);
  copy_agg_kernel<<<B_, 256, 0, stream>>>(stw, enc_out, agg, replist, repcnt);
  copy_score1_kernel<<<B_*L_, 128, 0, stream>>>(src_tokens, prev_tok, enc_out, copy_W, dstate, scopy);
  copy_softmax_state_kernel<<<B_, 256, 0, stream>>>(scopy, enc_out, cstate);
  dec_step_kernel<<<B_, 512, 0, stream>>>(prev_tok, emb, cstate, dec_Wih, dec_b, rnn);
  attn_kernel<<<B_, 256, 0, stream>>>(src_tokens, rnn, enc_out, attn_W, out_W, out_b, attn_out);
  gen_logits_kernel<<<(NV_+63)/64, 256, 0, stream>>>(attn_out, gen_W, oovc, total);
  copy_score2_kernel<<<dim3(B_,32), 128, 0, stream>>>(stw, agg, copy_W, attn_out, replist, repcnt, total);
  vocab_pass1_kernel<<<dim3(B_,32), 256, 0, stream>>>(total, pmax, psum);
  vocab_pass2_kernel<<<B_, 32, 0, stream>>>(pmax, psum, MZ);
  vocab_pass3_kernel<<<dim3(B_,32), 256, 0, stream>>>(total, MZ);
}

// Round 2
// 340.818 us; speedup vs baseline: 1.2529x; 1.2529x over previous
//
#include <hip/hip_runtime.h>
#include <math.h>

#define B_   16
#define L_   256
#define V_   50000
#define NV_  50100
#define E_   128
#define H_   128
#define G4_  512
#define CHUNK_ 1566   // ceil(50100/32)

typedef float f32x4 __attribute__((ext_vector_type(4)));
typedef float f32x2 __attribute__((ext_vector_type(2)));

__device__ __forceinline__ float sigm(float x){ return 1.0f/(1.0f+__expf(-x)); }
__device__ __forceinline__ float tanh_fast(float x){
  x = fminf(15.0f, fmaxf(-15.0f, x));
  float t = __expf(2.0f*x);
  return (t-1.0f)/(t+1.0f);
}

// ---------------- K1: encoder xg = emb[tok] @ W_ih^T + b ----------------
__global__ __launch_bounds__(512) void enc_xg_kernel(
    const int* __restrict__ tok, const float* __restrict__ emb,
    const float* __restrict__ Wih, const float* __restrict__ bias,
    float* __restrict__ xg)
{
  __shared__ __align__(16) float sx[8*128];
  int r0 = blockIdx.x*8;
  int t = threadIdx.x;
  for (int i=t; i<8*128; i+=512){
    int r=i>>7, e=i&127;
    sx[i] = emb[(size_t)tok[r0+r]*E_ + e];
  }
  __syncthreads();
  int g = t;
  float acc[8];
  #pragma unroll
  for (int r=0;r<8;r++) acc[r]=0.f;
  const float4* wr = (const float4*)(Wih + (size_t)g*E_);
  #pragma unroll 4
  for (int i=0;i<32;i++){
    float4 w = wr[i];
    #pragma unroll
    for (int r=0;r<8;r++){
      float4 x = ((const float4*)(sx + r*128))[i];
      acc[r] += w.x*x.x + w.y*x.y + w.z*x.z + w.w*x.w;
    }
  }
  float bg = bias[g];
  #pragma unroll
  for (int r=0;r<8;r++) xg[(size_t)(r0+r)*G4_ + g] = acc[r] + bg;
}

// ---------------- K2: encoder LSTM recurrence ----------------
// 16 blocks (one per batch), 512 threads (one gate each).
// __launch_bounds__(512,2): 2 waves/EU -> 256 VGPR budget so W_hh row stays
// resident in registers (f32x2 w2[64] = 128 VGPRs). R1 had VGPR_Count=80 ->
// compiler was re-loading W every step.
__global__ __launch_bounds__(512, 2) void enc_lstm_kernel(
    const float* __restrict__ xg, const float* __restrict__ Whh,
    float* __restrict__ enc_out)
{
  int b = blockIdx.x;
  int g = threadIdx.x;
  f32x2 w2[64];
  {
    const f32x4* wr4 = (const f32x4*)(Whh + (size_t)g*H_);
    #pragma unroll
    for (int k=0;k<32;k++){
      f32x4 wv = wr4[k];
      w2[2*k]   = wv.xy;
      w2[2*k+1] = wv.zw;
    }
  }

  __shared__ __align__(16) float sh_h[128];
  __shared__ float sh_g[512];
  if (g<128) sh_h[g]=0.f;
  float c = 0.f;
  const float* xgb = xg + (size_t)b*L_*G4_;
  float* eob = enc_out + (size_t)b*L_*H_;
  __syncthreads();

  const f32x4* sh4 = (const f32x4*)sh_h;
  bool is_gg = (g>=256 && g<384);   // tanh gate (wave-uniform)
  float xcur = xgb[g];
  for (int t=0;t<L_;t++){
    float xnext = (t<L_-1) ? xgb[(t+1)*G4_ + g] : 0.f;  // prefetch
    f32x2 a0 = {xcur, 0.f}, a1 = {0.f,0.f}, a2 = {0.f,0.f}, a3 = {0.f,0.f};
    #pragma unroll
    for (int k=0;k<32;k+=4){
      f32x4 h0=sh4[k], h1=sh4[k+1], h2v=sh4[k+2], h3=sh4[k+3];
      a0 += w2[2*k+0]*h0.xy;  a1 += w2[2*k+1]*h0.zw;
      a2 += w2[2*k+2]*h1.xy;  a3 += w2[2*k+3]*h1.zw;
      a0 += w2[2*k+4]*h2v.xy; a1 += w2[2*k+5]*h2v.zw;
      a2 += w2[2*k+6]*h3.xy;  a3 += w2[2*k+7]*h3.zw;
    }
    f32x2 as = (a0+a1)+(a2+a3);
    float acc = as.x + as.y;
    // per-gate nonlinearity in the parallel section (wave-uniform branch)
    float act = is_gg ? tanh_fast(acc) : sigm(acc);
    sh_g[g] = act;
    __syncthreads();
    if (g < 128){
      c = sh_g[128+g]*c + sh_g[g]*sh_g[256+g];
      float h = sh_g[384+g]*tanh_fast(c);
      sh_h[g] = h;
      eob[t*H_ + g] = h;
    }
    __syncthreads();
    xcur = xnext;
  }
}

// ---------------- K3: copy-attention raw scores ----------------
__global__ __launch_bounds__(128) void copy_score1_kernel(
    const int* __restrict__ src, const int* __restrict__ prev,
    const float* __restrict__ enc_out, const float* __restrict__ cW,
    const float* __restrict__ dstate, float* __restrict__ s)
{
  int bl = blockIdx.x; int b = bl>>8;
  if (src[bl] != prev[b]){ if (threadIdx.x==0) s[bl]=0.f; return; }
  __shared__ __align__(16) float se[128];
  __shared__ float sred[2];
  int g = threadIdx.x;
  se[g] = enc_out[(size_t)bl*H_ + g];
  __syncthreads();
  const float4* wr = (const float4*)(cW + (size_t)g*H_);
  float acc=0.f;
  #pragma unroll
  for (int i=0;i<32;i++){
    float4 wv=wr[i]; float4 e=((const float4*)se)[i];
    acc += wv.x*e.x + wv.y*e.y + wv.z*e.z + wv.w*e.w;
  }
  float v = tanhf(acc)*dstate[b*H_+g];
  #pragma unroll
  for (int o=32;o;o>>=1) v += __shfl_down(v,o);
  if ((g&63)==0) sred[g>>6]=v;
  __syncthreads();
  if (g==0) s[bl]=sred[0]+sred[1];
}

// ---------------- K4+K5+K6 fused: copy softmax/state + dec step + attention ----------------
__global__ __launch_bounds__(512) void fuse_mid_kernel(
    const float* __restrict__ scopy, const float* __restrict__ enc_out,
    const int* __restrict__ prev, const float* __restrict__ emb,
    const float* __restrict__ dWih, const float* __restrict__ db,
    const int* __restrict__ src, const float* __restrict__ aW,
    const float* __restrict__ oW, const float* __restrict__ ob,
    float* __restrict__ attn_out)
{
  int b=blockIdx.x, t=threadIdx.x;
  __shared__ float sw[256];
  __shared__ float spart[512];
  __shared__ float sred[4];
  __shared__ __align__(16) float sin_[256];
  __shared__ float sg[512];
  __shared__ __align__(16) float sr[128];
  __shared__ __align__(16) float sq[128];
  __shared__ float sc[256];
  __shared__ __align__(16) float sctx[128];

  // ---- A1: softmax over copy scores (t<256 active) ----
  float v = (t<256) ? scopy[b*L_+t] : -INFINITY;
  {
    float m=v;
    #pragma unroll
    for (int o=32;o;o>>=1) m=fmaxf(m,__shfl_down(m,o));
    if (t<256 && (t&63)==0) sred[t>>6]=m;
  }
  __syncthreads();
  float m4 = fmaxf(fmaxf(sred[0],sred[1]),fmaxf(sred[2],sred[3]));
  __syncthreads();
  float e = (t<256) ? __expf(v-m4) : 0.f;
  {
    float z=e;
    #pragma unroll
    for (int o=32;o;o>>=1) z += __shfl_down(z,o);
    if (t<256 && (t&63)==0) sred[t>>6]=z;
  }
  __syncthreads();
  {
    float z4 = sred[0]+sred[1]+sred[2]+sred[3];
    if (t<256) sw[t] = e/z4;
  }
  __syncthreads();

  // ---- A2: copy_state = sum_l sw[l]*enc_out[b,l,:] (all 512 threads) ----
  {
    int ch=t>>7, h=t&127;
    float acc=0.f;
    const float* eb = enc_out + (size_t)b*L_*H_;
    for (int l=ch*64; l<ch*64+64; l++) acc += sw[l]*eb[(size_t)l*H_+h];
    spart[t]=acc;
  }
  __syncthreads();
  if (t<128){
    float cst = spart[t]+spart[128+t]+spart[256+t]+spart[384+t];
    sin_[128+t]=cst;
    sin_[t]=emb[(size_t)prev[b]*E_+t];
  }
  __syncthreads();

  // ---- B: decoder single LSTM step (h0=c0=0) ----
  {
    const f32x4* wr=(const f32x4*)(dWih + (size_t)t*256);
    const f32x4* x4=(const f32x4*)sin_;
    f32x2 d0={db[t],0.f}, d1={0.f,0.f}, d2={0.f,0.f}, d3={0.f,0.f};
    #pragma unroll
    for (int k=0;k<64;k+=4){
      f32x4 xa=x4[k], xb=x4[k+1], xc=x4[k+2], xd=x4[k+3];
      f32x4 wa=wr[k], wb=wr[k+1], wc=wr[k+2], wd=wr[k+3];
      d0 += wa.xy*xa.xy; d1 += wa.zw*xa.zw;
      d2 += wb.xy*xb.xy; d3 += wb.zw*xb.zw;
      d0 += wc.xy*xc.xy; d1 += wc.zw*xc.zw;
      d2 += wd.xy*xd.xy; d3 += wd.zw*xd.zw;
    }
    f32x2 dsm=(d0+d1)+(d2+d3);
    sg[t]=dsm.x+dsm.y;
  }
  __syncthreads();
  if (t<128){
    float iv=sg[t], gv=sg[256+t], ov=sg[384+t];   // f-gate * c0 = 0
    float cc = sigm(iv)*tanhf(gv);
    sr[t] = sigm(ov)*tanhf(cc);
  }
  __syncthreads();

  // ---- C1: q = attn_W @ rnn ----
  if (t<128){
    const f32x4* wr=(const f32x4*)(aW + (size_t)t*H_);
    const f32x4* x4=(const f32x4*)sr;
    float acc=0.f;
    #pragma unroll
    for (int i=0;i<32;i++){
      f32x4 wv=wr[i], x=x4[i];
      acc += wv.x*x.x + wv.y*x.y + wv.z*x.z + wv.w*x.w;
    }
    sq[t]=acc;
  }
  __syncthreads();

  // ---- C2: scores + mask ----
  if (t<256){
    const f32x4* e4=(const f32x4*)(enc_out + ((size_t)b*L_+t)*H_);
    const f32x4* q4=(const f32x4*)sq;
    float acc=0.f;
    #pragma unroll
    for (int i=0;i<32;i++){
      f32x4 ev=e4[i], q=q4[i];
      acc += ev.x*q.x + ev.y*q.y + ev.z*q.z + ev.w*q.w;
    }
    if (src[b*L_+t]==0) acc=-INFINITY;
    sc[t]=acc;
  }
  __syncthreads();

  // ---- attn softmax over sc ----
  v = (t<256) ? sc[t] : -INFINITY;
  {
    float m=v;
    #pragma unroll
    for (int o=32;o;o>>=1) m=fmaxf(m,__shfl_down(m,o));
    if (t<256 && (t&63)==0) sred[t>>6]=m;
  }
  __syncthreads();
  m4 = fmaxf(fmaxf(sred[0],sred[1]),fmaxf(sred[2],sred[3]));
  __syncthreads();
  e = (t<256) ? __expf(v-m4) : 0.f;
  {
    float z=e;
    #pragma unroll
    for (int o=32;o;o>>=1) z += __shfl_down(z,o);
    if (t<256 && (t&63)==0) sred[t>>6]=z;
  }
  __syncthreads();
  {
    float z4 = sred[0]+sred[1]+sred[2]+sred[3];
    if (t<256) sc[t] = e/z4;
  }
  __syncthreads();

  // ---- C3: ctx = sum_l aw[l]*enc_out[b,l,:] ----
  {
    int ch=t>>7, h=t&127;
    float acc=0.f;
    const float* eb = enc_out + (size_t)b*L_*H_;
    for (int l=ch*64; l<ch*64+64; l++) acc += sc[l]*eb[(size_t)l*H_+h];
    spart[t]=acc;
  }
  __syncthreads();
  if (t<128) sctx[t] = spart[t]+spart[128+t]+spart[256+t]+spart[384+t];
  __syncthreads();

  // ---- C4: attn_out = tanh(out_W @ [rnn,ctx] + out_b) ----
  if (t<128){
    const f32x4* wr=(const f32x4*)(oW + (size_t)t*256);
    const f32x4* r4=(const f32x4*)sr;
    const f32x4* c4=(const f32x4*)sctx;
    float acc=ob[t];
    #pragma unroll
    for (int i=0;i<32;i++){
      f32x4 wv=wr[i], x=r4[i];
      acc += wv.x*x.x + wv.y*x.y + wv.z*x.z + wv.w*x.w;
    }
    #pragma unroll
    for (int i=0;i<32;i++){
      f32x4 wv=wr[32+i], x=c4[i];
      acc += wv.x*x.x + wv.y*x.y + wv.z*x.z + wv.w*x.w;
    }
    attn_out[b*H_+t]=tanhf(acc);
  }
}

// ---------------- K7a: first-occurrence aggregation of enc_out by token ----------------
__global__ __launch_bounds__(256) void copy_agg_kernel(
    const int* __restrict__ stw, const float* __restrict__ enc_out,
    float* __restrict__ agg, int* __restrict__ replist, int* __restrict__ repcnt)
{
  int b=blockIdx.x, l=threadIdx.x;
  __shared__ int stok[256];
  __shared__ int scnt;
  stok[l] = stw[b*L_+l];
  if (l==0) scnt=0;
  __syncthreads();
  int tok = stok[l];
  int first=0;
  while (stok[first]!=tok) first++;
  if (first==l){
    int myidx = atomicAdd(&scnt,1);
    float4 acc[32];
    #pragma unroll
    for (int i=0;i<32;i++) acc[i]=make_float4(0.f,0.f,0.f,0.f);
    for (int l2=l; l2<L_; l2++){
      if (stok[l2]==tok){
        const float4* e=(const float4*)(enc_out + ((size_t)b*L_+l2)*H_);
        #pragma unroll
        for (int i=0;i<32;i++){
          float4 v=e[i];
          acc[i].x+=v.x; acc[i].y+=v.y; acc[i].z+=v.z; acc[i].w+=v.w;
        }
      }
    }
    float4* dst=(float4*)(agg + ((size_t)b*L_+l)*H_);
    #pragma unroll
    for (int i=0;i<32;i++) dst[i]=acc[i];
    replist[b*L_+myidx]=l;
  }
  __syncthreads();
  if (l==0) repcnt[b]=scnt;
}

// ---------------- K9: gen logits + masks -> total ----------------
__global__ __launch_bounds__(256) void gen_logits_kernel(
    const float* __restrict__ attn_out, const float* __restrict__ gW,
    const int* __restrict__ oovc, float* __restrict__ total)
{
  __shared__ float sa[B_*H_];
  __shared__ float sw[64*129];
  int t=threadIdx.x;
  int v0=blockIdx.x*64;
  for (int i=t;i<B_*H_;i+=256) sa[i]=attn_out[i];
  for (int i=t;i<64*32;i+=256){
    int r=i>>5, cc=i&31;
    if (v0+r<NV_){
      float4 wv = ((const float4*)(gW + (size_t)(v0+r)*H_))[cc];
      float* dst = sw + r*129 + cc*4;
      dst[0]=wv.x; dst[1]=wv.y; dst[2]=wv.z; dst[3]=wv.w;
    }
  }
  __syncthreads();
  int vl=t&63, bq=t>>6;
  int v=v0+vl;
  if (v>=NV_) return;
  float acc[4]={0.f,0.f,0.f,0.f};
  const float* wrow = sw + vl*129;
  #pragma unroll 8
  for (int h4=0; h4<32; h4++){
    float w0=wrow[h4*4+0], w1=wrow[h4*4+1], w2=wrow[h4*4+2], w3=wrow[h4*4+3];
    #pragma unroll
    for (int k=0;k<4;k++){
      float4 a = ((const float4*)(sa + (bq*4+k)*H_))[h4];
      acc[k] += w0*a.x + w1*a.y + w2*a.z + w3*a.w;
    }
  }
  #pragma unroll
  for (int k=0;k<4;k++){
    int b=bq*4+k;
    float o = (v==1 || v >= V_ + oovc[b]) ? -INFINITY : acc[k];
    total[(size_t)b*NV_ + v] = o;
  }
}

// ---------------- K7b: sparse copy scores added into total ----------------
__global__ __launch_bounds__(128) void copy_score2_kernel(
    const int* __restrict__ stw, const float* __restrict__ agg,
    const float* __restrict__ cW, const float* __restrict__ attn_out,
    const int* __restrict__ replist, const int* __restrict__ repcnt,
    float* __restrict__ total)
{
  int b=blockIdx.x;
  int cnt=repcnt[b];
  int g=threadIdx.x;
  __shared__ __align__(16) float srow[128];
  __shared__ float sred[2];
  float aog = attn_out[b*H_+g];
  float4 w[32];
  const float4* wrow=(const float4*)(cW + (size_t)g*H_);
  #pragma unroll
  for (int i=0;i<32;i++) w[i]=wrow[i];
  for (int ri=blockIdx.y; ri<cnt; ri+=gridDim.y){
    int l = replist[b*L_+ri];
    srow[g] = agg[((size_t)b*L_+l)*H_+g];
    __syncthreads();
    float acc=0.f;
    #pragma unroll
    for (int i=0;i<32;i++){
      float4 e=((const float4*)srow)[i]; float4 wv=w[i];
      acc += wv.x*e.x + wv.y*e.y + wv.z*e.z + wv.w*e.w;
    }
    float v = tanhf(acc)*aog;
    #pragma unroll
    for (int o=32;o;o>>=1) v += __shfl_down(v,o);
    if ((g&63)==0) sred[g>>6]=v;
    __syncthreads();
    if (g==0){
      int vtok = stw[b*L_+l];
      total[(size_t)b*NV_ + vtok] += sred[0]+sred[1];
    }
    __syncthreads();
  }
}

// ---------------- K10: vocab softmax (chunked two-pass) ----------------
__global__ __launch_bounds__(256) void vocab_pass1_kernel(
    const float* __restrict__ total, float* __restrict__ pmax, float* __restrict__ psum)
{
  int b=blockIdx.x, j=blockIdx.y, t=threadIdx.x;
  int lo=j*CHUNK_, hi=min(lo+CHUNK_, NV_);
  const float* row = total + (size_t)b*NV_;
  __shared__ float sred[4];
  float m=-INFINITY;
  for (int i=lo+t;i<hi;i+=256) m=fmaxf(m,row[i]);
  #pragma unroll
  for (int o=32;o;o>>=1) m=fmaxf(m,__shfl_down(m,o));
  if ((t&63)==0) sred[t>>6]=m;
  __syncthreads();
  m = fmaxf(fmaxf(sred[0],sred[1]),fmaxf(sred[2],sred[3]));
  __syncthreads();
  float s=0.f;
  if (m > -INFINITY){
    for (int i=lo+t;i<hi;i+=256) s += __expf(row[i]-m);
    #pragma unroll
    for (int o=32;o;o>>=1) s += __shfl_down(s,o);
  }
  if ((t&63)==0) sred[t>>6]=s;
  __syncthreads();
  if (t==0){ pmax[b*32+j]=m; psum[b*32+j]=sred[0]+sred[1]+sred[2]+sred[3]; }
}

__global__ void vocab_pass2_kernel(const float* __restrict__ pmax,
                                   const float* __restrict__ psum, float* __restrict__ MZ)
{
  int b=blockIdx.x, t=threadIdx.x; // 32 threads
  float mj = pmax[b*32+t];
  float m = mj;
  #pragma unroll
  for (int o=16;o;o>>=1) m=fmaxf(m,__shfl_down(m,o));
  m = __shfl(m,0);
  float z = psum[b*32+t]*__expf(mj-m);
  #pragma unroll
  for (int o=16;o;o>>=1) z += __shfl_down(z,o);
  if (t==0){ MZ[b]=m; MZ[16+b]=z; }
}

__global__ __launch_bounds__(256) void vocab_pass3_kernel(
    float* __restrict__ total, const float* __restrict__ MZ)
{
  int b=blockIdx.x, j=blockIdx.y, t=threadIdx.x;
  int lo=j*CHUNK_, hi=min(lo+CHUNK_, NV_);
  float m=MZ[b], rz=1.0f/MZ[16+b];
  float* row = total + (size_t)b*NV_;
  for (int i=lo+t;i<hi;i+=256) row[i] = __expf(row[i]-m)*rz;
}

// ---------------- launch ----------------
extern "C" void kernel_launch(void* const* d_in, const int* in_sizes, int n_in,
                              void* d_out, int out_size, void* d_ws, size_t ws_size,
                              hipStream_t stream)
{
  const int*   src_tokens = (const int*)d_in[0];
  const int*   prev_tok   = (const int*)d_in[2];
  const int*   stw        = (const int*)d_in[4];
  const int*   oovc       = (const int*)d_in[5];
  const float* dstate     = (const float*)d_in[6];
  const float* emb        = (const float*)d_in[7];
  const float* enc_Wih    = (const float*)d_in[8];
  const float* enc_Whh    = (const float*)d_in[9];
  const float* enc_b      = (const float*)d_in[10];
  const float* dec_Wih    = (const float*)d_in[11];
  const float* dec_b      = (const float*)d_in[13];
  const float* attn_W     = (const float*)d_in[14];
  const float* out_W      = (const float*)d_in[15];
  const float* out_b      = (const float*)d_in[16];
  const float* copy_W     = (const float*)d_in[17];
  const float* gen_W      = (const float*)d_in[18];

  float* out      = (float*)d_out;
  float* total    = out;                                 // B*NV
  float* enc_out  = out + (size_t)B_*NV_;                // B*L*H
  float* attn_out = enc_out + (size_t)B_*L_*H_;          // B*H

  float* ws     = (float*)d_ws;
  float* xg     = ws;                                    // B*L*G4
  float* agg    = xg + (size_t)B_*L_*G4_;                // B*L*H
  float* scopy  = agg + (size_t)B_*L_*H_;                // B*L
  float* pmax   = scopy + B_*L_;                         // 512
  float* psum   = pmax + 512;                            // 512
  float* MZ     = psum + 512;                            // 32
  int*   replist= (int*)(MZ + 32);                       // B*L
  int*   repcnt = replist + B_*L_;                       // 16

  enc_xg_kernel<<<B_*L_/8, 512, 0, stream>>>(src_tokens, emb, enc_Wih, enc_b, xg);
  enc_lstm_kernel<<<B_, 512, 0, stream>>>(xg, enc_Whh, enc_out);
  copy_score1_kernel<<<B_*L_, 128, 0, stream>>>(src_tokens, prev_tok, enc_out, copy_W, dstate, scopy);
  copy_agg_kernel<<<B_, 256, 0, stream>>>(stw, enc_out, agg, replist, repcnt);
  fuse_mid_kernel<<<B_, 512, 0, stream>>>(scopy, enc_out, prev_tok, emb, dec_Wih, dec_b,
                                          src_tokens, attn_W, out_W, out_b, attn_out);
  gen_logits_kernel<<<(NV_+63)/64, 256, 0, stream>>>(attn_out, gen_W, oovc, total);
  copy_score2_kernel<<<dim3(B_,32), 128, 0, stream>>>(stw, agg, copy_W, attn_out, replist, repcnt, total);
  vocab_pass1_kernel<<<dim3(B_,32), 256, 0, stream>>>(total, pmax, psum);
  vocab_pass2_kernel<<<B_, 32, 0, stream>>>(pmax, psum, MZ);
  vocab_pass3_kernel<<<dim3(B_,32), 256, 0, stream>>>(total, MZ);
}